// Round 1
// baseline (169.039 us; speedup 1.0000x reference)
//
#include <hip/hip_runtime.h>
#include <hip/hip_bf16.h>
#include <cstdint>

#define BB 64
#define NN 512
#define MM 1024
#define DD 128

typedef __bf16 bf16x8 __attribute__((ext_vector_type(8)));
typedef float f32x4 __attribute__((ext_vector_type(4)));
typedef short s16x4 __attribute__((ext_vector_type(4)));

static __device__ __forceinline__ unsigned short f2bf(float f) {
    union { float f; unsigned int i; } v; v.f = f;
    unsigned int x = v.i;
    x += 0x7FFFu + ((x >> 16) & 1u);   // RNE
    return (unsigned short)(x >> 16);
}
// packed v_cvt_pk_bf16_f32: low = a, high = b
static __device__ __forceinline__ unsigned int f2bf2(float a, float b) {
    union { __hip_bfloat162 h; unsigned int u; } c;
    c.h = __float22bfloat162_rn(make_float2(a, b));
    return c.u;
}

// ---------- Kernel 1: Vp = relu(h_p @ Wv^T + b) ------------------------------
// Outputs: Vp row-major tiles [b][mt][64][128], VpT tiled [b][mt][128][64].
__global__ __launch_bounds__(256, 4) void proj_v_kernel(
    const float* __restrict__ X,
    const float* __restrict__ Wv,
    const float* __restrict__ bias,
    unsigned short* __restrict__ Y,
    unsigned short* __restrict__ YT)
{
    __shared__ __align__(16) unsigned short Ws[128 * 136];   // 34816 B, reused
    unsigned short* Ys = Ws;            // 64*128 shorts
    unsigned short* Ts = Ws + 8192;     // 128*72 shorts
    const int t = threadIdx.x;
    const int lane = t & 63;
    const int wave = t >> 6;
    const int n16 = lane & 15, q = lane >> 4;
    const long row0 = (long)blockIdx.x * 64;

    // X loads FIRST (latency overlaps W staging below)
    float4 xv[8];
    {
        const float* xrow = X + (row0 + wave * 16 + n16) * DD + q * 8;
        #pragma unroll
        for (int kk = 0; kk < 4; ++kk) {
            xv[2 * kk]     = *(const float4*)(xrow + kk * 32);
            xv[2 * kk + 1] = *(const float4*)(xrow + kk * 32 + 4);
        }
    }

    // stage Wv fp32 -> bf16 into padded LDS
    {
        const float4* Wg = (const float4*)Wv;
        #pragma unroll
        for (int i = 0; i < 16; ++i) {
            int idx = i * 256 + t;            // 4096 float4
            float4 v = Wg[idx];
            int off = idx * 4;                // shorts
            uint2 u = { f2bf2(v.x, v.y), f2bf2(v.z, v.w) };
            *(uint2*)&Ws[(off >> 7) * 136 + (off & 127)] = u;
        }
    }
    __syncthreads();

    f32x4 acc[8];
    #pragma unroll
    for (int j = 0; j < 8; ++j) acc[j] = {0.f, 0.f, 0.f, 0.f};

    #pragma unroll
    for (int kk = 0; kk < 4; ++kk) {
        float4 x0 = xv[2 * kk], x1 = xv[2 * kk + 1];
        union { bf16x8 v; unsigned int u[4]; } a;
        a.u[0] = f2bf2(x0.x, x0.y); a.u[1] = f2bf2(x0.z, x0.w);
        a.u[2] = f2bf2(x1.x, x1.y); a.u[3] = f2bf2(x1.z, x1.w);
        #pragma unroll
        for (int j = 0; j < 8; ++j) {
            bf16x8 b = *(const bf16x8*)&Ws[(j * 16 + n16) * 136 + q * 8 + kk * 32];
            acc[j] = __builtin_amdgcn_mfma_f32_16x16x32_bf16(a.v, b, acc[j], 0, 0, 0);
        }
    }

    unsigned short yb[8][4];
    #pragma unroll
    for (int j = 0; j < 8; ++j) {
        const float bv = bias[j * 16 + n16];
        float y[4];
        #pragma unroll
        for (int r = 0; r < 4; ++r) {
            float v = acc[j][r] + bv;
            y[r] = v > 0.f ? v : 0.f;
        }
        uint2 u = { f2bf2(y[0], y[1]), f2bf2(y[2], y[3]) };
        *(uint2*)&yb[j][0] = u;
    }
    __syncthreads();   // Ws reads done; reuse as Ys/Ts

    #pragma unroll
    for (int j = 0; j < 8; ++j) {
        const int e = j * 16 + n16;
        #pragma unroll
        for (int r = 0; r < 4; ++r)
            Ys[(wave * 16 + q * 4 + r) * 128 + e] = yb[j][r];
        *(uint2*)&Ts[e * 72 + wave * 16 + q * 4] = *(uint2*)&yb[j][0];
    }
    __syncthreads();

    {
        uint4* dstY = (uint4*)(Y + row0 * DD);
        const long b = row0 >> 10;
        const long mt = (row0 & 1023) >> 6;
        uint4* dstT = (uint4*)(YT + ((b * 16 + mt) * 128) * 64);
        #pragma unroll
        for (int i = 0; i < 4; ++i) {
            int idx = i * 256 + t;
            dstY[idx] = ((const uint4*)Ys)[idx];
            int e = idx >> 3, m = (idx & 7) * 8;
            dstT[idx] = *(const uint4*)&Ts[e * 72 + m];
        }
    }
}

// ---------- Kernel 2: fused proj_c + bilinear attention ----------------------
// Grid 512 = (b, nt); 4 waves. Phase 1: Uc = relu(h_c Wu^T + b), stored in LDS
// PRE-SCALED by log2(e); fp32 unscaled row-sums (ucred) kept in regs.
//
// Main loop (REWRITTEN — barrier-free): per mt, each wave owns 16 m-rows.
//  QK (m-split, 16x16x32): A = Vp rows m read DIRECT from global (L2-hot,
//    register double-buffered one tile ahead), B = Uc rows from LDS.
//    Output at lane (n16,q): P[n=j*16+n16][m=w*16+q*4+r].
//  KEY: that is EXACTLY the A-fragment layout of v_mfma_f32_16x16x16_bf16
//    (lane (n16,q) holds A[row=n16][k=q*4+e]) with k = the wave's 16 m-rows.
//    So PV runs m-split with ZERO cross-wave exchange: no Ps, no barriers.
//  PV (16x16x16, k=16): B = VpT[d][m] frags (8 B/lane) direct from global.
//  O_w[n][d] partials (4x8 f32x4 = 128 VGPR) reduced cross-wave in epilogue:
//    sum_n inv[n]*(sum_w O_w) == sum_w (sum_n inv[n]*O_w)  -> commutes.
// No LDS V staging, no DMA, no main-loop __syncthreads at all: 8 independent
// wave streams per CU hide L2 latency by construction.
static __device__ __forceinline__ void attn_step(
    int mt,
    const unsigned short* __restrict__ vpb,
    const unsigned short* __restrict__ vtb,
    const unsigned short* Ucs,
    int a_off, int vt_off, int ucs_off,
    bf16x8 (&aC)[4], bf16x8 (&aN)[4],
    f32x4 (&O)[4][8], float (&lpart)[4])
{
    // PV B-frags for this tile: VpT[d = dj*16+n16][m = w*16+q*4 .. +3]
    s16x4 bf[8];
    {
        const unsigned short* tb = vtb + mt * 8192 + vt_off;
        #pragma unroll
        for (int dj = 0; dj < 8; ++dj)
            bf[dj] = *(const s16x4*)(tb + dj * 1024);
    }
    // prefetch next tile's QK A-frags (consumed next call; clamp avoids OOB)
    {
        int nx = mt + 1; if (nx > 15) nx = 15;
        const unsigned short* pa = vpb + nx * 8192 + a_off;
        #pragma unroll
        for (int kk = 0; kk < 4; ++kk)
            aN[kk] = *(const bf16x8*)(pa + kk * 32);
    }

    // QK: S^T[m][n], rows m = w*16+q*4+r, cols n = j*16+n16
    f32x4 S[4];
    #pragma unroll
    for (int j = 0; j < 4; ++j) S[j] = {0.f, 0.f, 0.f, 0.f};
    #pragma unroll
    for (int kk = 0; kk < 4; ++kk) {
        #pragma unroll
        for (int j = 0; j < 4; ++j) {
            bf16x8 bg = *(const bf16x8*)&Ucs[j * (16 * 136) + ucs_off + kk * 32];
            S[j] = __builtin_amdgcn_mfma_f32_16x16x32_bf16(aC[kk], bg, S[j], 0, 0, 0);
        }
    }

    // p = exp2(S) (Uc pre-scaled); pack directly into PV A-frags (in-register!)
    s16x4 av[4];
    #pragma unroll
    for (int j = 0; j < 4; ++j) {
        float p0 = __builtin_exp2f(S[j][0]);
        float p1 = __builtin_exp2f(S[j][1]);
        float p2 = __builtin_exp2f(S[j][2]);
        float p3 = __builtin_exp2f(S[j][3]);
        lpart[j] += (p0 + p1) + (p2 + p3);
        union { unsigned int u[2]; s16x4 v; } pk;
        pk.u[0] = f2bf2(p0, p1); pk.u[1] = f2bf2(p2, p3);
        av[j] = pk.v;
    }

    // PV (m-split, k = this wave's 16 m): O[n=j*16+q*4+r][d=dj*16+n16]
    #pragma unroll
    for (int dj = 0; dj < 8; ++dj) {
        #pragma unroll
        for (int j = 0; j < 4; ++j)
            O[j][dj] = __builtin_amdgcn_mfma_f32_16x16x16bf16_1k(
                av[j], bf[dj], O[j][dj], 0, 0, 0);
    }
}

__global__ __launch_bounds__(256, 2) void attn_kernel(
    const float* __restrict__ hc,             // (B*512,128) fp32
    const float* __restrict__ Wu,             // (128,128) fp32
    const float* __restrict__ Ub,             // (128) fp32
    const unsigned short* __restrict__ Vp,    // (B,16,64,128) bf16 tiled
    const unsigned short* __restrict__ VpT,   // (B,16,128,64) bf16 tiled
    float* __restrict__ part)                 // (B*8,128) fp32
{
    // shorts: Ws[0,17408) (phase-1 W, epilogue float scratch) Ucs[17408,26112)
    __shared__ __align__(16) unsigned short smem[26112];   // 52224 B
    unsigned short* Ws  = smem;
    unsigned short* Ucs = smem + 17408;

    const int t = threadIdx.x;
    const int lane = t & 63;
    const int wave = t >> 6;
    const int n16 = lane & 15, q = lane >> 4;

    const int id = blockIdx.x;
    const int xcd = id & 7;
    const int slot = id >> 3;
    const int b = xcd * 8 + (slot >> 3);
    const int nt = slot & 7;

    const unsigned short* vpb = Vp + (long)b * MM * DD;    // 16 tiles of 8192
    const unsigned short* vtb = VpT + (long)b * MM * DD;

    const float LOG2E = 1.44269504088896f;

    // ---- Phase 1: Uc for this block's 64 n-rows (Wu fp32 -> bf16 in LDS) ----
    {
        const float4* Wg = (const float4*)Wu;
        #pragma unroll
        for (int i = 0; i < 16; ++i) {
            int idx = i * 256 + t;
            float4 v = Wg[idx];
            int off = idx * 4;
            uint2 u = { f2bf2(v.x, v.y), f2bf2(v.z, v.w) };
            *(uint2*)&Ws[(off >> 7) * 136 + (off & 127)] = u;
        }
    }
    __syncthreads();

    f32x4 acc[8];
    #pragma unroll
    for (int j = 0; j < 8; ++j) acc[j] = {0.f, 0.f, 0.f, 0.f};
    {
        const float* xrow = hc + ((long)b * NN + nt * 64 + wave * 16 + n16) * DD + q * 8;
        #pragma unroll
        for (int kk = 0; kk < 4; ++kk) {
            float4 x0 = *(const float4*)(xrow + kk * 32);
            float4 x1 = *(const float4*)(xrow + kk * 32 + 4);
            union { bf16x8 v; unsigned int u[4]; } a;
            a.u[0] = f2bf2(x0.x, x0.y); a.u[1] = f2bf2(x0.z, x0.w);
            a.u[2] = f2bf2(x1.x, x1.y); a.u[3] = f2bf2(x1.z, x1.w);
            #pragma unroll
            for (int j = 0; j < 8; ++j) {
                bf16x8 bb = *(const bf16x8*)&Ws[(j * 16 + n16) * 136 + q * 8 + kk * 32];
                acc[j] = __builtin_amdgcn_mfma_f32_16x16x32_bf16(a.v, bb, acc[j], 0, 0, 0);
            }
        }
    }
    float ucred[8];
    #pragma unroll
    for (int j = 0; j < 8; ++j) {
        const float bv = Ub[j * 16 + n16];
        float s = 0.f;
        #pragma unroll
        for (int r = 0; r < 4; ++r) {
            float v = acc[j][r] + bv;
            v = v > 0.f ? v : 0.f;
            s += v;
            // store Uc * log2(e): QK output feeds exp2 directly
            Ucs[(wave * 16 + q * 4 + r) * 136 + j * 16 + n16] = f2bf(v * LOG2E);
        }
        ucred[j] = s;
    }
    __syncthreads();                      // Ucs ready; last barrier before epilogue

    // ---- Main loop: barrier-free ----
    f32x4 O[4][8];
    #pragma unroll
    for (int j = 0; j < 4; ++j)
        #pragma unroll
        for (int dj = 0; dj < 8; ++dj) O[j][dj] = {0.f, 0.f, 0.f, 0.f};
    float lpart[4] = {0.f, 0.f, 0.f, 0.f};

    const int a_off  = (wave * 16 + n16) * 128 + q * 8;   // Vp tile: A frag
    const int vt_off = n16 * 64 + wave * 16 + q * 4;      // VpT tile: B frag
    const int ucs_off = n16 * 136 + q * 8;                // Ucs: QK B frag

    bf16x8 aA[4], aB[4];
    #pragma unroll
    for (int kk = 0; kk < 4; ++kk)
        aA[kk] = *(const bf16x8*)&vpb[a_off + kk * 32];

    #pragma unroll 1
    for (int mt = 0; mt < 16; mt += 2) {
        attn_step(mt,     vpb, vtb, Ucs, a_off, vt_off, ucs_off, aA, aB, O, lpart);
        attn_step(mt + 1, vpb, vtb, Ucs, a_off, vt_off, ucs_off, aB, aA, O, lpart);
    }

    // ---- Epilogue: l reduction, inv, weighted O reduction ----
    // lpart[j] covers n = j*16+n16 over this wave's m rows & its q slice
    #pragma unroll
    for (int j = 0; j < 4; ++j) {
        lpart[j] += __shfl_xor(lpart[j], 16);
        lpart[j] += __shfl_xor(lpart[j], 32);
    }
    float* lred = (float*)Ws;               // 256 floats (per-wave l partials)
    float* invs = lred + 256;               // 64 floats
    float* red  = lred + 320;               // 512 floats
    if (q == 0) {
        #pragma unroll
        for (int j = 0; j < 4; ++j)
            lred[wave * 64 + j * 16 + n16] = lpart[j];
    }
    __syncthreads();
    if (t < 64)
        invs[t] = 1.0f / (lred[t] + lred[64 + t] + lred[128 + t] + lred[192 + t]);
    __syncthreads();

    float iv[4][4];
    #pragma unroll
    for (int j = 0; j < 4; ++j)
        #pragma unroll
        for (int r = 0; r < 4; ++r)
            iv[j][r] = invs[j * 16 + q * 4 + r];

    // s[d] = ucred + sum_n inv[n]*O_w[n][d]; reduce over q then cross-wave
    #pragma unroll
    for (int dj = 0; dj < 8; ++dj) {
        float s = ucred[dj];
        #pragma unroll
        for (int j = 0; j < 4; ++j) {
            s += O[j][dj][0] * iv[j][0] + O[j][dj][1] * iv[j][1]
               + O[j][dj][2] * iv[j][2] + O[j][dj][3] * iv[j][3];
        }
        s += __shfl_xor(s, 16);
        s += __shfl_xor(s, 32);
        if (q == 0)
            red[wave * 128 + dj * 16 + n16] = s;
    }
    __syncthreads();
    if (t < 128) {
        float tot = red[t] + red[128 + t] + red[256 + t] + red[384 + t];
        part[(long)(b * 8 + nt) * DD + t] = tot;
    }
}

// ---------- Kernel 3: out[b][d] = (Sigma_nt part) * q[d] / N -----------------
__global__ __launch_bounds__(256) void finalize_kernel(
    const float* __restrict__ part, const float* __restrict__ qv,
    float* __restrict__ out)
{
    int i = blockIdx.x * 256 + threadIdx.x;     // 8192
    int b = i >> 7, d = i & 127;
    const float* p = part + (long)b * 8 * DD + d;
    float s = 0.f;
    #pragma unroll
    for (int nt = 0; nt < 8; ++nt) s += p[nt * DD];
    out[i] = s * qv[d] * (1.0f / (float)NN);
}

extern "C" void kernel_launch(void* const* d_in, const int* in_sizes, int n_in,
                              void* d_out, int out_size, void* d_ws, size_t ws_size,
                              hipStream_t stream) {
    const float* h_c = (const float*)d_in[0];
    const float* h_p = (const float*)d_in[1];
    const float* U_w = (const float*)d_in[2];
    const float* U_b = (const float*)d_in[3];
    const float* V_w = (const float*)d_in[4];
    const float* V_b = (const float*)d_in[5];
    const float* qv  = (const float*)d_in[6];
    float* out = (float*)d_out;

    unsigned short* Vp  = (unsigned short*)d_ws;                 // (B,16,64,128) bf16
    unsigned short* VpT = Vp + (size_t)BB * MM * DD;             // (B,16,128,64) bf16
    float* part = (float*)(VpT + (size_t)BB * MM * DD);          // (B*8,128) fp32

    proj_v_kernel<<<BB * MM / 64, 256, 0, stream>>>(h_p, V_w, V_b, Vp, VpT);
    attn_kernel<<<512, 256, 0, stream>>>(h_c, U_w, U_b, Vp, VpT, part);
    finalize_kernel<<<32, 256, 0, stream>>>(part, qv, out);
}

// Round 2
// 133.662 us; speedup vs baseline: 1.2647x; 1.2647x over previous
//
#include <hip/hip_runtime.h>
#include <hip/hip_bf16.h>
#include <cstdint>

#define BB 64
#define NN 512
#define MM 1024
#define DD 128

typedef __bf16 bf16x8 __attribute__((ext_vector_type(8)));
typedef float f32x4 __attribute__((ext_vector_type(4)));

static __device__ __forceinline__ unsigned short f2bf(float f) {
    union { float f; unsigned int i; } v; v.f = f;
    unsigned int x = v.i;
    x += 0x7FFFu + ((x >> 16) & 1u);   // RNE
    return (unsigned short)(x >> 16);
}
// packed v_cvt_pk_bf16_f32: low = a, high = b
static __device__ __forceinline__ unsigned int f2bf2(float a, float b) {
    union { __hip_bfloat162 h; unsigned int u; } c;
    c.h = __float22bfloat162_rn(make_float2(a, b));
    return c.u;
}
// async global->LDS DMA, 16 B per lane, dest = wave-uniform base + lane*16
static __device__ __forceinline__ void async16(const void* g, void* l) {
    __builtin_amdgcn_global_load_lds(
        (const __attribute__((address_space(1))) void*)g,
        (__attribute__((address_space(3))) void*)l, 16, 0, 0);
}

// ---------- Kernel 1: Vp = relu(h_p @ Wv^T + b) ------------------------------
// Outputs: Vp row-major tiles [b][mt][64][128], VpT tiled [b][mt][128][64].
__global__ __launch_bounds__(256, 4) void proj_v_kernel(
    const float* __restrict__ X,
    const float* __restrict__ Wv,
    const float* __restrict__ bias,
    unsigned short* __restrict__ Y,
    unsigned short* __restrict__ YT)
{
    __shared__ __align__(16) unsigned short Ws[128 * 136];   // 34816 B, reused
    unsigned short* Ys = Ws;            // 64*128 shorts
    unsigned short* Ts = Ws + 8192;     // 128*72 shorts
    const int t = threadIdx.x;
    const int lane = t & 63;
    const int wave = t >> 6;
    const int n16 = lane & 15, q = lane >> 4;
    const long row0 = (long)blockIdx.x * 64;

    // X loads FIRST (latency overlaps W staging below)
    float4 xv[8];
    {
        const float* xrow = X + (row0 + wave * 16 + n16) * DD + q * 8;
        #pragma unroll
        for (int kk = 0; kk < 4; ++kk) {
            xv[2 * kk]     = *(const float4*)(xrow + kk * 32);
            xv[2 * kk + 1] = *(const float4*)(xrow + kk * 32 + 4);
        }
    }

    // stage Wv fp32 -> bf16 into padded LDS
    {
        const float4* Wg = (const float4*)Wv;
        #pragma unroll
        for (int i = 0; i < 16; ++i) {
            int idx = i * 256 + t;            // 4096 float4
            float4 v = Wg[idx];
            int off = idx * 4;                // shorts
            uint2 u = { f2bf2(v.x, v.y), f2bf2(v.z, v.w) };
            *(uint2*)&Ws[(off >> 7) * 136 + (off & 127)] = u;
        }
    }
    __syncthreads();

    f32x4 acc[8];
    #pragma unroll
    for (int j = 0; j < 8; ++j) acc[j] = {0.f, 0.f, 0.f, 0.f};

    #pragma unroll
    for (int kk = 0; kk < 4; ++kk) {
        float4 x0 = xv[2 * kk], x1 = xv[2 * kk + 1];
        union { bf16x8 v; unsigned int u[4]; } a;
        a.u[0] = f2bf2(x0.x, x0.y); a.u[1] = f2bf2(x0.z, x0.w);
        a.u[2] = f2bf2(x1.x, x1.y); a.u[3] = f2bf2(x1.z, x1.w);
        #pragma unroll
        for (int j = 0; j < 8; ++j) {
            bf16x8 b = *(const bf16x8*)&Ws[(j * 16 + n16) * 136 + q * 8 + kk * 32];
            acc[j] = __builtin_amdgcn_mfma_f32_16x16x32_bf16(a.v, b, acc[j], 0, 0, 0);
        }
    }

    unsigned short yb[8][4];
    #pragma unroll
    for (int j = 0; j < 8; ++j) {
        const float bv = bias[j * 16 + n16];
        float y[4];
        #pragma unroll
        for (int r = 0; r < 4; ++r) {
            float v = acc[j][r] + bv;
            y[r] = v > 0.f ? v : 0.f;
        }
        uint2 u = { f2bf2(y[0], y[1]), f2bf2(y[2], y[3]) };
        *(uint2*)&yb[j][0] = u;
    }
    __syncthreads();   // Ws reads done; reuse as Ys/Ts

    #pragma unroll
    for (int j = 0; j < 8; ++j) {
        const int e = j * 16 + n16;
        #pragma unroll
        for (int r = 0; r < 4; ++r)
            Ys[(wave * 16 + q * 4 + r) * 128 + e] = yb[j][r];
        *(uint2*)&Ts[e * 72 + wave * 16 + q * 4] = *(uint2*)&yb[j][0];
    }
    __syncthreads();

    {
        uint4* dstY = (uint4*)(Y + row0 * DD);
        const long b = row0 >> 10;
        const long mt = (row0 & 1023) >> 6;
        uint4* dstT = (uint4*)(YT + ((b * 16 + mt) * 128) * 64);
        #pragma unroll
        for (int i = 0; i < 4; ++i) {
            int idx = i * 256 + t;
            dstY[idx] = ((const uint4*)Ys)[idx];
            int e = idx >> 3, m = (idx & 7) * 8;
            dstT[idx] = *(const uint4*)&Ts[e * 72 + m];
        }
    }
}

// ---------- Kernel 2: fused proj_c + bilinear attention ----------------------
// Grid 512 = (b, nt); 4 waves. Phase 1: Uc = relu(h_c Wu^T + b), stored in LDS
// PRE-SCALED by log2(e); Bg (all 64 Uc rows) hoisted to registers; fp32
// unscaled row-sums (ucred) in regs.
//
// Main loop: m-split QK / n-split PV with Ps exchange (round-0 structure), but:
//  - QK A-frags read DIRECT global->reg (wave-private rows; no LDS, no sharing),
//    register double-buffered one tile ahead.  QK has ZERO LDS reads.
//  - Only VpT staged in LDS (cross-wave reused 4x), via DMA into a TRIPLE
//    buffer, issued at the TOP of the iteration TWO tiles ahead (~2 iters of
//    latency cover).
//  - barrier1 (Ps exchange) is lgkmcnt-only: DMA stays in flight across it.
//  - barrier2 waits vmcnt(8) (counted, never 0): drains DMA(mt+1) (needed next
//    iter), keeps this iter's 8 newest vmem ops (4 DMA + 4 A-prefetch) in
//    flight.  In-order vmcnt retirement makes this safe even with extra vmem.
//  - s_setprio(1) around MFMA clusters (T5).
static __device__ __forceinline__ void bar_lgkm() {
    asm volatile("s_waitcnt lgkmcnt(0)" ::: "memory");
    __builtin_amdgcn_s_barrier();
    __builtin_amdgcn_sched_barrier(0);
}
static __device__ __forceinline__ void bar_vm8() {
    asm volatile("s_waitcnt vmcnt(8) lgkmcnt(0)" ::: "memory");
    __builtin_amdgcn_s_barrier();
    __builtin_amdgcn_sched_barrier(0);
}

static __device__ __forceinline__ void attn_iter(
    int mt, unsigned short* smem, unsigned short* Ps,
    const unsigned short* __restrict__ vpb,
    const unsigned short* __restrict__ vtb,
    int wave, int lane, int n16, int q, int a_off,
    const bf16x8 (&Bg)[4][4],
    bf16x8 (&aC)[4], bf16x8 (&aN)[4],
    f32x4 (&O)[8], float (&lpart)[4])
{
    // top: DMA VpT tile mt+2 into buf[(mt+2)%3] (clamped reissue keeps vmcnt
    // counting uniform; redundant restage of tile 15 is never read)
    {
        int nx = mt + 2; if (nx > 15) nx = 15;
        const unsigned short* st = vtb + nx * 8192;
        unsigned short* dst = smem + ((mt + 2) % 3) * 8192 + wave * 2048;
        #pragma unroll
        for (int i = 0; i < 4; ++i) {
            int L = wave * 256 + i * 64 + lane;
            int r = L >> 3, sc = L & 7, c = sc ^ (r & 7);
            async16(st + r * 64 + c * 8, dst + i * 512);
        }
    }
    // A-frag prefetch for tile mt+1 (global->reg, consumed next iteration)
    {
        int nx = mt + 1; if (nx > 15) nx = 15;
        const unsigned short* pa = vpb + nx * 8192 + a_off;
        #pragma unroll
        for (int kk = 0; kk < 4; ++kk)
            aN[kk] = *(const bf16x8*)(pa + kk * 32);
    }

    // QK (m-split): S^T rows m = wave*16+q*4+r, cols n = j*16+n16. Pure regs.
    f32x4 S[4];
    #pragma unroll
    for (int j = 0; j < 4; ++j) S[j] = {0.f, 0.f, 0.f, 0.f};
    __builtin_amdgcn_s_setprio(1);
    #pragma unroll
    for (int kk = 0; kk < 4; ++kk) {
        #pragma unroll
        for (int j = 0; j < 4; ++j)
            S[j] = __builtin_amdgcn_mfma_f32_16x16x32_bf16(aC[kk], Bg[j][kk], S[j], 0, 0, 0);
    }
    __builtin_amdgcn_s_setprio(0);

    // p = exp2(S) (Uc pre-scaled); write P[n][m] slices to shared Ps
    #pragma unroll
    for (int j = 0; j < 4; ++j) {
        float p0 = __builtin_exp2f(S[j][0]);
        float p1 = __builtin_exp2f(S[j][1]);
        float p2 = __builtin_exp2f(S[j][2]);
        float p3 = __builtin_exp2f(S[j][3]);
        lpart[j] += (p0 + p1) + (p2 + p3);
        uint2 u = { f2bf2(p0, p1), f2bf2(p2, p3) };
        *(uint2*)&Ps[(j * 16 + n16) * 72 + wave * 16 + q * 4] = u;
    }
    bar_lgkm();   // barrier 1: P complete; DMA + prefetch stay in flight

    // PV (n-split): O[n][d] for this wave's 16 n-rows; VTs from current buffer
    const unsigned short* VTs = smem + (mt % 3) * 8192;
    __builtin_amdgcn_s_setprio(1);
    #pragma unroll
    for (int kk = 0; kk < 2; ++kk) {
        bf16x8 a = *(const bf16x8*)&Ps[(wave * 16 + n16) * 72 + kk * 32 + q * 8];
        #pragma unroll
        for (int j = 0; j < 8; ++j) {
            bf16x8 bb = *(const bf16x8*)&VTs[(j * 16 + n16) * 64 + ((kk * 4 + q) ^ (n16 & 7)) * 8];
            O[j] = __builtin_amdgcn_mfma_f32_16x16x32_bf16(a, bb, O[j], 0, 0, 0);
        }
    }
    __builtin_amdgcn_s_setprio(0);
    bar_vm8();    // barrier 2: Ps/VTs reads done; DMA(mt+1) drained; 8 newest in flight
}

__global__ __launch_bounds__(256, 2) void attn_kernel(
    const float* __restrict__ hc,             // (B*512,128) fp32
    const float* __restrict__ Wu,             // (128,128) fp32
    const float* __restrict__ Ub,             // (128) fp32
    const unsigned short* __restrict__ Vp,    // (B,16,64,128) bf16 tiled
    const unsigned short* __restrict__ VpT,   // (B,16,128,64) bf16 tiled
    float* __restrict__ part)                 // (B*8,128) fp32
{
    // shorts: buf0[0,8192) buf1[8192,16384) buf2[16384,24576) Ps[24576,29184)
    // Phase-1 alias: Ws[0,17408), Ucs[17408,26112) (dead after Bg load).
    __shared__ __align__(16) unsigned short smem[29184];   // 58368 B
    unsigned short* Ws  = smem;
    unsigned short* Ucs = smem + 17408;
    unsigned short* Ps  = smem + 24576;

    const int t = threadIdx.x;
    const int lane = t & 63;
    const int wave = t >> 6;
    const int n16 = lane & 15, q = lane >> 4;

    const int id = blockIdx.x;
    const int xcd = id & 7;
    const int slot = id >> 3;
    const int b = xcd * 8 + (slot >> 3);
    const int nt = slot & 7;

    const unsigned short* vpb = Vp + (long)b * MM * DD;    // 16 tiles of 8192
    const unsigned short* vtb = VpT + (long)b * MM * DD;

    const float LOG2E = 1.44269504088896f;

    // ---- Phase 1: Uc for this block's 64 n-rows (Wu fp32 -> bf16 in LDS) ----
    {
        const float4* Wg = (const float4*)Wu;
        #pragma unroll
        for (int i = 0; i < 16; ++i) {
            int idx = i * 256 + t;
            float4 v = Wg[idx];
            int off = idx * 4;
            uint2 u = { f2bf2(v.x, v.y), f2bf2(v.z, v.w) };
            *(uint2*)&Ws[(off >> 7) * 136 + (off & 127)] = u;
        }
    }
    __syncthreads();

    f32x4 acc[8];
    #pragma unroll
    for (int j = 0; j < 8; ++j) acc[j] = {0.f, 0.f, 0.f, 0.f};
    {
        const float* xrow = hc + ((long)b * NN + nt * 64 + wave * 16 + n16) * DD + q * 8;
        #pragma unroll
        for (int kk = 0; kk < 4; ++kk) {
            float4 x0 = *(const float4*)(xrow + kk * 32);
            float4 x1 = *(const float4*)(xrow + kk * 32 + 4);
            union { bf16x8 v; unsigned int u[4]; } a;
            a.u[0] = f2bf2(x0.x, x0.y); a.u[1] = f2bf2(x0.z, x0.w);
            a.u[2] = f2bf2(x1.x, x1.y); a.u[3] = f2bf2(x1.z, x1.w);
            #pragma unroll
            for (int j = 0; j < 8; ++j) {
                bf16x8 bb = *(const bf16x8*)&Ws[(j * 16 + n16) * 136 + q * 8 + kk * 32];
                acc[j] = __builtin_amdgcn_mfma_f32_16x16x32_bf16(a.v, bb, acc[j], 0, 0, 0);
            }
        }
    }
    float ucred[8];
    #pragma unroll
    for (int j = 0; j < 8; ++j) {
        const float bv = Ub[j * 16 + n16];
        float s = 0.f;
        #pragma unroll
        for (int r = 0; r < 4; ++r) {
            float v = acc[j][r] + bv;
            v = v > 0.f ? v : 0.f;
            s += v;
            // store Uc * log2(e): QK output feeds exp2 directly
            Ucs[(wave * 16 + q * 4 + r) * 136 + j * 16 + n16] = f2bf(v * LOG2E);
        }
        ucred[j] = s;
    }
    __syncthreads();                          // (A): Ucs ready, Ws reads drained

    // ALL 64 n-rows of Uc as B-frags in registers (16 frags = 64 VGPRs)
    bf16x8 Bg[4][4];
    #pragma unroll
    for (int j = 0; j < 4; ++j)
        #pragma unroll
        for (int kk = 0; kk < 4; ++kk)
            Bg[j][kk] = *(const bf16x8*)&Ucs[(j * 16 + n16) * 136 + q * 8 + kk * 32];

    // Prologue: A-frags tile 0 + DMA VpT tiles 0,1 into buf0,buf1
    const int a_off = (wave * 16 + n16) * 128 + q * 8;
    bf16x8 aA[4], aB[4];
    #pragma unroll
    for (int kk = 0; kk < 4; ++kk)
        aA[kk] = *(const bf16x8*)&vpb[a_off + kk * 32];
    #pragma unroll
    for (int tt = 0; tt < 2; ++tt) {
        const unsigned short* st = vtb + tt * 8192;
        unsigned short* dst = smem + tt * 8192 + wave * 2048;
        #pragma unroll
        for (int i = 0; i < 4; ++i) {
            int L = wave * 256 + i * 64 + lane;
            int r = L >> 3, sc = L & 7, c = sc ^ (r & 7);
            async16(st + r * 64 + c * 8, dst + i * 512);
        }
    }
    // (C): DMA(0) drained (4 newest = DMA(1) stay in flight); Bg/Ucs reads done
    asm volatile("s_waitcnt vmcnt(4) lgkmcnt(0)" ::: "memory");
    __builtin_amdgcn_s_barrier();
    __builtin_amdgcn_sched_barrier(0);

    // ---- Main loop ----
    f32x4 O[8];
    #pragma unroll
    for (int j = 0; j < 8; ++j) O[j] = {0.f, 0.f, 0.f, 0.f};
    float lpart[4] = {0.f, 0.f, 0.f, 0.f};

    #pragma unroll 1
    for (int mt = 0; mt < 16; mt += 2) {
        attn_iter(mt,     smem, Ps, vpb, vtb, wave, lane, n16, q, a_off, Bg, aA, aB, O, lpart);
        attn_iter(mt + 1, smem, Ps, vpb, vtb, wave, lane, n16, q, a_off, Bg, aB, aA, O, lpart);
    }

    // ---- l reduction: lpart[j] covers n = j*16+n16 over this wave's m & q ----
    #pragma unroll
    for (int j = 0; j < 4; ++j) {
        lpart[j] += __shfl_xor(lpart[j], 16);
        lpart[j] += __shfl_xor(lpart[j], 32);
    }
    float* lred = (float*)Ps;               // 256 floats
    float* red  = (float*)Ps + 256;         // 512 floats
    if (q == 0) {
        #pragma unroll
        for (int j = 0; j < 4; ++j)
            lred[wave * 64 + j * 16 + n16] = lpart[j];
    }
    __syncthreads();

    float inv[4];
    #pragma unroll
    for (int r = 0; r < 4; ++r) {
        int n = wave * 16 + q * 4 + r;
        inv[r] = 1.0f / (lred[n] + lred[64 + n] + lred[128 + n] + lred[192 + n]);
    }

    // per-wave partial over its 16 n-rows, then cross-wave reduction
    #pragma unroll
    for (int j = 0; j < 8; ++j) {
        float s = ucred[j]
                + O[j][0] * inv[0] + O[j][1] * inv[1]
                + O[j][2] * inv[2] + O[j][3] * inv[3];
        s += __shfl_xor(s, 16);
        s += __shfl_xor(s, 32);
        if (q == 0)
            red[wave * 128 + j * 16 + n16] = s;
    }
    __syncthreads();
    if (t < 128) {
        float tot = red[t] + red[128 + t] + red[256 + t] + red[384 + t];
        part[(long)(b * 8 + nt) * DD + t] = tot;
    }
}

// ---------- Kernel 3: out[b][d] = (Sigma_nt part) * q[d] / N -----------------
__global__ __launch_bounds__(256) void finalize_kernel(
    const float* __restrict__ part, const float* __restrict__ qv,
    float* __restrict__ out)
{
    int i = blockIdx.x * 256 + threadIdx.x;     // 8192
    int b = i >> 7, d = i & 127;
    const float* p = part + (long)b * 8 * DD + d;
    float s = 0.f;
    #pragma unroll
    for (int nt = 0; nt < 8; ++nt) s += p[nt * DD];
    out[i] = s * qv[d] * (1.0f / (float)NN);
}

extern "C" void kernel_launch(void* const* d_in, const int* in_sizes, int n_in,
                              void* d_out, int out_size, void* d_ws, size_t ws_size,
                              hipStream_t stream) {
    const float* h_c = (const float*)d_in[0];
    const float* h_p = (const float*)d_in[1];
    const float* U_w = (const float*)d_in[2];
    const float* U_b = (const float*)d_in[3];
    const float* V_w = (const float*)d_in[4];
    const float* V_b = (const float*)d_in[5];
    const float* qv  = (const float*)d_in[6];
    float* out = (float*)d_out;

    unsigned short* Vp  = (unsigned short*)d_ws;                 // (B,16,64,128) bf16
    unsigned short* VpT = Vp + (size_t)BB * MM * DD;             // (B,16,128,64) bf16
    float* part = (float*)(VpT + (size_t)BB * MM * DD);          // (B*8,128) fp32

    proj_v_kernel<<<BB * MM / 64, 256, 0, stream>>>(h_p, V_w, V_b, Vp, VpT);
    attn_kernel<<<512, 256, 0, stream>>>(h_c, U_w, U_b, Vp, VpT, part);
    finalize_kernel<<<32, 256, 0, stream>>>(part, qv, out);
}